// Round 3
// baseline (138.781 us; speedup 1.0000x reference)
//
#include <hip/hip_runtime.h>

#define NN 8192
#define LL 512
#define ZCAP (2u << 20)
#define NT 8   // K-tiles of 64

typedef __bf16 bf16x8 __attribute__((ext_vector_type(8)));
typedef float f32x4 __attribute__((ext_vector_type(4)));
typedef unsigned short ushort8v __attribute__((ext_vector_type(8)));

__device__ __forceinline__ unsigned short f2bf(float f) {
    unsigned u = __builtin_bit_cast(unsigned, f);
    unsigned r = 0x7FFFu + ((u >> 16) & 1u);
    return (unsigned short)((u + r) >> 16);
}

// ---------------- K1: row norms -> xn(bf16), xw = x@pool_rel_w, xr = x@pool_root_w
__global__ __launch_bounds__(256) void k_prep(const float* __restrict__ x,
        const float* __restrict__ relw, const float* __restrict__ rootw,
        unsigned short* __restrict__ xn, float* __restrict__ xw, float* __restrict__ xr)
{
    int w = threadIdx.x >> 6, lane = threadIdx.x & 63;
    int row = blockIdx.x * 4 + w;
    const float* xp = x + (size_t)row * LL + lane * 8;
    float4 a = *(const float4*)xp;
    float4 b = *(const float4*)(xp + 4);
    float v[8] = {a.x, a.y, a.z, a.w, b.x, b.y, b.z, b.w};
    float ss = 0.f, w0 = 0.f, w1 = 0.f, r0 = 0.f, r1 = 0.f;
    #pragma unroll
    for (int e = 0; e < 8; e++) {
        int k = lane * 8 + e;
        ss += v[e] * v[e];
        w0 += v[e] * relw[k * 2];  w1 += v[e] * relw[k * 2 + 1];
        r0 += v[e] * rootw[k * 2]; r1 += v[e] * rootw[k * 2 + 1];
    }
    #pragma unroll
    for (int off = 32; off > 0; off >>= 1) {
        ss += __shfl_xor(ss, off);
        w0 += __shfl_xor(w0, off); w1 += __shfl_xor(w1, off);
        r0 += __shfl_xor(r0, off); r1 += __shfl_xor(r1, off);
    }
    float inv = 1.0f / fmaxf(sqrtf(ss), 1e-6f);
    ushort8v p;
    #pragma unroll
    for (int e = 0; e < 8; e++) p[e] = f2bf(v[e] * inv);
    *(ushort8v*)(xn + (size_t)row * LL + lane * 8) = p;
    if (lane == 0) {
        xw[row * 2] = w0; xw[row * 2 + 1] = w1;
        xr[row * 2] = r0; xr[row * 2 + 1] = r1;
    }
}

// ---------------- column sums of xw -> sc[0], sc[9]
__global__ void k_sums(const float* __restrict__ xw, float* __restrict__ sc)
{
    int i = blockIdx.x * 256 + threadIdx.x;
    float s0 = xw[i * 2], s1 = xw[i * 2 + 1];
    #pragma unroll
    for (int off = 32; off > 0; off >>= 1) {
        s0 += __shfl_xor(s0, off); s1 += __shfl_xor(s1, off);
    }
    if ((threadIdx.x & 63) == 0) {
        atomicAdd(&sc[0], s0); atomicAdd(&sc[9], s1);
    }
}

// ---------------- K2: 256^2-tile 8-phase triangular sim GEMM; emit below-threshold pairs.
__global__ __launch_bounds__(512, 2) void k_sim(const unsigned short* __restrict__ xn,
                                                unsigned* __restrict__ zlist,
                                                float* __restrict__ sc)
{
    extern __shared__ char lds[];   // A0|B0|A1|B1, 32 KiB each; halves of 16 KiB
    int idx = (blockIdx.x & 7) * 66 + (blockIdx.x >> 3);   // XCD swizzle (528 = 8*66)
    int bi, bj;
    if (idx < 496) {               // strict-upper pairs first, diagonals last
        int b = idx, r = 0, len = 31;
        while (b >= len) { b -= len; len--; r++; }
        bi = r; bj = r + 1 + b;
    } else { bi = idx - 496; bj = bi; }
    const bool diag = (bi == bj);

    const int tid = threadIdx.x, w = tid >> 6, lane = tid & 63;
    const int wm = w >> 2, wn = w & 3;
    const int fr = lane & 15, fq = lane >> 4;

    // staging geometry: 16B chunk cI within a 16 KiB half; LDS(row,j) <- global(row, j^(row&7))
    const int cI0 = w * 64 + lane;
    const int rl0 = cI0 >> 3, js0 = (cI0 & 7) ^ (rl0 & 7);
    const int goff0 = rl0 * 1024 + js0 * 16;               // bytes within [128 x 64] half panel
    const int goff1 = goff0 + 65536;                       // rows 64..127 (same chunk xor)
    const int dw = w * 1024;

    const char* Aglc = (const char*)xn + (size_t)bi * 262144;
    const char* Bglc = (const char*)xn + (size_t)bj * 262144;

    auto stage_half = [&](const char* gbase, char* dbase, int kt) {
        __builtin_amdgcn_global_load_lds(
            (const __attribute__((address_space(1))) void*)(gbase + kt * 128 + goff0),
            (__attribute__((address_space(3))) void*)(dbase + dw), 16, 0, 0);
        __builtin_amdgcn_global_load_lds(
            (const __attribute__((address_space(1))) void*)(gbase + kt * 128 + goff1),
            (__attribute__((address_space(3))) void*)(dbase + 8192 + dw), 16, 0, 0);
    };
    auto STAGE = [&](int kt, int sel) {
        char* base = lds + sel * 65536;
        stage_half(Aglc,          base,         kt);
        stage_half(Aglc + 131072, base + 16384, kt);
        if (!diag) {
            stage_half(Bglc,          base + 32768, kt);
            stage_half(Bglc + 131072, base + 49152, kt);
        }
    };

    f32x4 zero = {0.f, 0.f, 0.f, 0.f};
    f32x4 acc[8][4];
    #pragma unroll
    for (int M = 0; M < 8; M++)
        #pragma unroll
        for (int N = 0; N < 4; N++) acc[M][N] = zero;

    STAGE(0, 0);

    for (int t = 0; t < NT; ++t) {
        const int sel = t & 1;
        __syncthreads();   // implicit vmcnt(0): tile t's loads (issued last tile) have landed
        const char* Ab = lds + sel * 65536 + wm * 16384;
        const char* Bb = lds + sel * 65536 + (diag ? 0 : 32768) + (wn >> 1) * 16384;
        bf16x8 af[4][2], bg[2][2];
        #pragma unroll
        for (int ph = 0; ph < 4; ++ph) {
            const int qm = ph >> 1, qn = ph & 1;
            const bool skipq = diag && (wm * 128 + qm * 64 > wn * 64 + qn * 32 + 31);
            const bool needA = !(diag && (wm * 128 + qm * 64 > wn * 64 + 63));
            if (qn == 0 && needA) {
                #pragma unroll
                for (int m = 0; m < 4; m++)
                    #pragma unroll
                    for (int kk = 0; kk < 2; kk++) {
                        int rl = qm * 64 + m * 16 + fr;
                        af[m][kk] = *(const bf16x8*)(Ab + rl * 128 + (((kk << 2) + fq) ^ (fr & 7)) * 16);
                    }
            }
            if (!skipq) {
                #pragma unroll
                for (int n = 0; n < 2; n++)
                    #pragma unroll
                    for (int kk = 0; kk < 2; kk++) {
                        int rl = (wn & 1) * 64 + qn * 32 + n * 16 + fr;
                        bg[n][kk] = *(const bf16x8*)(Bb + rl * 128 + (((kk << 2) + fq) ^ (fr & 7)) * 16);
                    }
            }
            if (ph == 0 && t + 1 < NT) STAGE(t + 1, sel ^ 1);
            __builtin_amdgcn_s_barrier();
            if (!skipq) {
                __builtin_amdgcn_s_setprio(1);
                #pragma unroll
                for (int m = 0; m < 4; m++)
                    #pragma unroll
                    for (int n = 0; n < 2; n++)
                        #pragma unroll
                        for (int kk = 0; kk < 2; kk++)
                            acc[qm * 4 + m][qn * 2 + n] = __builtin_amdgcn_mfma_f32_16x16x32_bf16(
                                af[m][kk], bg[n][kk], acc[qm * 4 + m][qn * 2 + n], 0, 0, 0);
                __builtin_amdgcn_s_setprio(0);
            }
            __builtin_amdgcn_s_barrier();
        }
    }

    // epilogue: emit below-threshold pairs (expected none). Upper-strict only; both orientations.
    unsigned* zcnt = (unsigned*)&sc[10];
    int rowb = bi * 256 + wm * 128, colb = bj * 256 + wn * 64;
    #pragma unroll
    for (int M = 0; M < 8; M++) {
        #pragma unroll
        for (int N = 0; N < 4; N++) {
            #pragma unroll
            for (int r = 0; r < 4; r++) {
                int grow = rowb + M * 16 + fq * 4 + r;
                int gcol = colb + N * 16 + fr;
                bool z = (acc[M][N][r] <= 0.5f) && (diag ? (grow < gcol) : true);
                if (__ballot(z)) {   // rare path
                    if (z) {
                        unsigned pos = atomicAdd(zcnt, 2u);
                        if (pos < ZCAP)     zlist[pos]     = ((unsigned)grow << 13) | (unsigned)gcol;
                        if (pos + 1 < ZCAP) zlist[pos + 1] = ((unsigned)gcol << 13) | (unsigned)grow;
                    }
                }
            }
        }
    }
}

// ---------------- s-path part 1: t = Sxw - xw - corr; y2 = leaky(t/deg + rel_b + xr); BN sums
__global__ void k_s1(const float* __restrict__ xw, const float* __restrict__ xr,
                     const float* __restrict__ relb, const unsigned* __restrict__ zlist,
                     float* __restrict__ sc, float* __restrict__ y2)
{
    int i = blockIdx.x * 256 + threadIdx.x;
    unsigned cnt = ((const unsigned*)sc)[10]; if (cnt > ZCAP) cnt = ZCAP;
    float corr0 = 0.f, corr1 = 0.f; int zc = 0;
    for (unsigned j = 0; j < cnt; j++) {
        unsigned e = zlist[j];
        if ((int)(e >> 13) == i) {
            unsigned c = e & 8191u;
            corr0 += xw[c * 2]; corr1 += xw[c * 2 + 1]; zc++;
        }
    }
    float d = fmaxf((float)(8191 - zc), 1.0f);
    float y0 = (sc[0] - xw[i * 2] - corr0) / d + relb[0] + xr[i * 2];
    float y1 = (sc[9] - xw[i * 2 + 1] - corr1) / d + relb[1] + xr[i * 2 + 1];
    y0 = y0 > 0.f ? y0 : 0.01f * y0;
    y1 = y1 > 0.f ? y1 : 0.01f * y1;
    y2[i * 2] = y0; y2[i * 2 + 1] = y1;
    float s0 = y0, s1 = y1, q0 = y0 * y0, q1 = y1 * y1;
    #pragma unroll
    for (int off = 32; off > 0; off >>= 1) {
        s0 += __shfl_xor(s0, off); s1 += __shfl_xor(s1, off);
        q0 += __shfl_xor(q0, off); q1 += __shfl_xor(q1, off);
    }
    if ((threadIdx.x & 63) == 0) {
        atomicAdd(&sc[1], s0); atomicAdd(&sc[2], s1);
        atomicAdd(&sc[3], q0); atomicAdd(&sc[4], q1);
    }
}

// ---------------- s-path part 2: BN apply + lin(2x2) + leaky + softmax -> s; ent/Gram/Ss sums
__global__ void k_s2(const float* __restrict__ y2, const float* __restrict__ bng,
                     const float* __restrict__ bnb, const float* __restrict__ linw,
                     const float* __restrict__ linb, float* __restrict__ s,
                     float* __restrict__ sc)
{
    int i = blockIdx.x * 256 + threadIdx.x;
    const float invN = 1.0f / NN;
    float m0 = sc[1] * invN, m1 = sc[2] * invN;
    float v0 = sc[3] * invN - m0 * m0, v1 = sc[4] * invN - m1 * m1;
    float c0 = rsqrtf(v0 + 1e-5f) * bng[0], c1 = rsqrtf(v1 + 1e-5f) * bng[1];
    float z0 = (y2[i * 2] - m0) * c0 + bnb[0];
    float z1 = (y2[i * 2 + 1] - m1) * c1 + bnb[1];
    float p0 = z0 * linw[0] + z1 * linw[2] + linb[0];
    float p1 = z0 * linw[1] + z1 * linw[3] + linb[1];
    p0 = p0 > 0.f ? p0 : 0.01f * p0;
    p1 = p1 > 0.f ? p1 : 0.01f * p1;
    float mx = fmaxf(p0, p1);
    float e0 = expf(p0 - mx), e1 = expf(p1 - mx);
    float inv = 1.0f / (e0 + e1);
    float s0 = e0 * inv, s1 = e1 * inv;
    s[i * 2] = s0; s[i * 2 + 1] = s1;
    float ent = -(s0 * logf(s0 + 1e-15f) + s1 * logf(s1 + 1e-15f));
    float g00 = s0 * s0, g01 = s0 * s1, g11 = s1 * s1;
    #pragma unroll
    for (int off = 32; off > 0; off >>= 1) {
        ent += __shfl_xor(ent, off);
        g00 += __shfl_xor(g00, off); g01 += __shfl_xor(g01, off); g11 += __shfl_xor(g11, off);
        s0 += __shfl_xor(s0, off);   s1 += __shfl_xor(s1, off);
    }
    if ((threadIdx.x & 63) == 0) {
        atomicAdd(&sc[5], g00); atomicAdd(&sc[6], g01);
        atomicAdd(&sc[7], g11); atomicAdd(&sc[8], ent);
        atomicAdd(&sc[11], s0); atomicAdd(&sc[12], s1);
    }
}

// ---------------- head matvec partials: av[t] += sum_k bnb3[k]*l1w[k,t] over k-slice
__global__ void k_head(const float* __restrict__ bnb3, const float* __restrict__ l1w,
                       float* __restrict__ av)
{
    int t = threadIdx.x, j = blockIdx.x;   // 8 blocks, 64 k each
    float acc = 0.f;
    #pragma unroll
    for (int k = j * 64; k < j * 64 + 64; k++) acc += bnb3[k] * l1w[k * 256 + t];
    atomicAdd(&av[t], acc);
}

// ---------------- final: relu+lin2+softmax; l1 (closed form) + e1
__global__ void k_final(const float* __restrict__ av, const float* __restrict__ l1b,
                        const float* __restrict__ l2w, const float* __restrict__ l2b,
                        const float* __restrict__ sc, const float* __restrict__ s,
                        const unsigned* __restrict__ zlist, float* __restrict__ out)
{
    __shared__ float hv[256];
    __shared__ float red[4];
    __shared__ float logits[4];
    int t = threadIdx.x;
    unsigned cnt = ((const unsigned*)sc)[10]; if (cnt > ZCAP) cnt = ZCAP;
    float zc_ = 0.f;
    for (unsigned j = t; j < cnt; j += 256) {
        unsigned e = zlist[j], r = e >> 13, c = e & 8191u;
        zc_ += s[r * 2] * s[c * 2] + s[r * 2 + 1] * s[c * 2 + 1];
    }
    #pragma unroll
    for (int off = 32; off > 0; off >>= 1) zc_ += __shfl_xor(zc_, off);
    if ((t & 63) == 0) red[t >> 6] = zc_;
    hv[t] = fmaxf(av[t] + l1b[t], 0.f);
    __syncthreads();
    if (t < 4) {
        float lg = l2b[t];
        for (int j = 0; j < 256; j++) lg += hv[j] * l2w[j * 4 + t];
        logits[t] = lg;
    }
    __syncthreads();
    if (t == 0) {
        float mx = fmaxf(fmaxf(logits[0], logits[1]), fmaxf(logits[2], logits[3]));
        float e[4], sum = 0.f;
        for (int c = 0; c < 4; c++) { e[c] = expf(logits[c] - mx); sum += e[c]; }
        for (int c = 0; c < 4; c++) out[c] = e[c] / sum;
        float zcorr = red[0] + red[1] + red[2] + red[3];
        float Ss0 = sc[11], Ss1 = sc[12];
        float G00 = sc[5], G01 = sc[6], G11 = sc[7];
        float tr2 = Ss0 * Ss0 + Ss1 * Ss1 - G00 - G11 - zcorr;
        float E = 8192.0f * 8191.0f - (float)cnt;
        float fro2 = fmaxf(E - 2.f * tr2 + (G00 * G00 + 2.f * G01 * G01 + G11 * G11), 0.f);
        out[4] = sqrtf(fro2) / (8192.0f * 8192.0f);
        out[5] = sc[8] * (1.0f / NN);
    }
}

extern "C" void kernel_launch(void* const* d_in, const int* in_sizes, int n_in,
                              void* d_out, int out_size, void* d_ws, size_t ws_size,
                              hipStream_t stream) {
    const float* x          = (const float*)d_in[0];
    const float* pool_rel_w = (const float*)d_in[1];
    const float* pool_rel_b = (const float*)d_in[2];
    const float* pool_root_w= (const float*)d_in[3];
    const float* pool_bn_g  = (const float*)d_in[4];
    const float* pool_bn_b  = (const float*)d_in[5];
    const float* pool_lin_w = (const float*)d_in[6];
    const float* pool_lin_b = (const float*)d_in[7];
    const float* emb3_bn_b  = (const float*)d_in[17];
    const float* lin1_w     = (const float*)d_in[18];
    const float* lin1_b     = (const float*)d_in[19];
    const float* lin2_w     = (const float*)d_in[20];
    const float* lin2_b     = (const float*)d_in[21];
    float* out = (float*)d_out;

    char* ws = (char*)d_ws;
    unsigned short* xn = (unsigned short*)ws;                  // 8 MB
    unsigned* zlist = (unsigned*)(ws + (size_t)(8u << 20));    // 8 MB
    float* xw = (float*)(ws + (size_t)(16u << 20));
    float* xr = xw + NN * 2;
    float* y2 = xr + NN * 2;
    float* s  = y2 + NN * 2;
    float* sc = s + NN * 2;          // 16 floats
    float* av = sc + 16;             // 256 floats

    if (ws_size < (size_t)17211456 + 256) return;

    hipFuncSetAttribute((const void*)k_sim, hipFuncAttributeMaxDynamicSharedMemorySize, 131072);

    hipMemsetAsync(sc, 0, (16 + 256) * sizeof(float), stream);
    k_prep<<<dim3(2048), dim3(256), 0, stream>>>(x, pool_rel_w, pool_root_w, xn, xw, xr);
    k_sums<<<dim3(32), dim3(256), 0, stream>>>(xw, sc);
    k_sim<<<dim3(528), dim3(512), 131072, stream>>>(xn, zlist, sc);
    k_s1<<<dim3(32), dim3(256), 0, stream>>>(xw, xr, pool_rel_b, zlist, sc, y2);
    k_s2<<<dim3(32), dim3(256), 0, stream>>>(y2, pool_bn_g, pool_bn_b, pool_lin_w, pool_lin_b, s, sc);
    k_head<<<dim3(8), dim3(256), 0, stream>>>(emb3_bn_b, lin1_w, av);
    k_final<<<dim3(1), dim3(256), 0, stream>>>(av, lin1_b, lin2_w, lin2_b, sc, s, zlist, out);
}

// Round 4
// 90.474 us; speedup vs baseline: 1.5339x; 1.5339x over previous
//
#include <hip/hip_runtime.h>

#define NN 8192
#define LL 512
#define ZCAP (2u << 20)

typedef float f32x4 __attribute__((ext_vector_type(4)));
typedef int i32x8 __attribute__((ext_vector_type(8)));
typedef unsigned long long u64;

// float -> fp8 e4m3fn (RNE), input in [0, ~6)
__device__ __forceinline__ unsigned f2fp8(float f) {
    if (f < 0.015625f) {                 // subnormal: steps of 2^-9
        return (unsigned)(int)rintf(f * 512.0f);   // 8 -> 0x08 = min normal, correct
    }
    unsigned u = __builtin_bit_cast(unsigned, f);
    unsigned r = u + 0x7FFFF + ((u >> 20) & 1);
    return ((r >> 20) - 960u) & 0xFFu;
}

// ---------------- K1: rows 0..8191: xn(fp8, x64 scale), xw = x@pool_rel_w, xr = x@pool_root_w
// blocks >= 2048: head matvec partials av[t] += sum_k bnb3[k]*l1w[k,t]
__global__ __launch_bounds__(256) void k_prep(const float* __restrict__ x,
        const float* __restrict__ relw, const float* __restrict__ rootw,
        const float* __restrict__ bnb3, const float* __restrict__ l1w,
        unsigned char* __restrict__ xn, float* __restrict__ xw, float* __restrict__ xr,
        float* __restrict__ av)
{
    if (blockIdx.x >= 2048) {
        int j = blockIdx.x - 2048, t = threadIdx.x;
        float acc = 0.f;
        #pragma unroll
        for (int k = j * 64; k < j * 64 + 64; k++) acc += bnb3[k] * l1w[k * 256 + t];
        atomicAdd(&av[t], acc);
        return;
    }
    int w = threadIdx.x >> 6, lane = threadIdx.x & 63;
    int row = blockIdx.x * 4 + w;
    const float* xp = x + (size_t)row * LL + lane * 8;
    float4 a = *(const float4*)xp;
    float4 b = *(const float4*)(xp + 4);
    float v[8] = {a.x, a.y, a.z, a.w, b.x, b.y, b.z, b.w};
    float ss = 0.f, w0 = 0.f, w1 = 0.f, r0 = 0.f, r1 = 0.f;
    #pragma unroll
    for (int e = 0; e < 8; e++) {
        int k = lane * 8 + e;
        ss += v[e] * v[e];
        w0 += v[e] * relw[k * 2];  w1 += v[e] * relw[k * 2 + 1];
        r0 += v[e] * rootw[k * 2]; r1 += v[e] * rootw[k * 2 + 1];
    }
    #pragma unroll
    for (int off = 32; off > 0; off >>= 1) {
        ss += __shfl_xor(ss, off);
        w0 += __shfl_xor(w0, off); w1 += __shfl_xor(w1, off);
        r0 += __shfl_xor(r0, off); r1 += __shfl_xor(r1, off);
    }
    float inv = 64.0f / fmaxf(sqrtf(ss), 1e-6f);   // x64: e4m3 normal range
    u64 pk = 0;
    #pragma unroll
    for (int e = 0; e < 8; e++) pk |= (u64)f2fp8(v[e] * inv) << (8 * e);
    *(u64*)(xn + (size_t)row * LL + lane * 8) = pk;
    if (lane == 0) {
        xw[row * 2] = w0; xw[row * 2 + 1] = w1;
        xr[row * 2] = r0; xr[row * 2 + 1] = r1;
    }
}

// ---------------- K2: sim*4096 = (64 xn)@(64 xn)^T via MX-fp8 MFMA (scale=1.0),
// triangular 128-tiles (bi<=bj); emit below-threshold off-diag pairs to zlist.
__global__ __launch_bounds__(256) void k_sim(const unsigned char* __restrict__ xn,
                                             unsigned* __restrict__ zlist,
                                             float* __restrict__ sc)
{
    __shared__ __align__(16) unsigned char As[128 * 128];
    __shared__ __align__(16) unsigned char Bs[128 * 128];
    int b = blockIdx.x, bi = 0, len = 64;
    while (b >= len) { b -= len; len--; bi++; }
    int bj = bi + b;
    const bool diag = (bi == bj);

    int t = threadIdx.x, w = t >> 6, lane = t & 63;
    int wr = w >> 1, wc = w & 1;
    int fr = lane & 15, fq = lane >> 4;

    f32x4 zero = {0.f, 0.f, 0.f, 0.f};
    f32x4 acc[4][4];
    #pragma unroll
    for (int m = 0; m < 4; m++)
        #pragma unroll
        for (int n = 0; n < 4; n++) acc[m][n] = zero;

    const unsigned char* Ab = xn + (size_t)bi * 128 * LL;
    const unsigned char* Bb = xn + (size_t)bj * 128 * LL;

    for (int kt = 0; kt < 4; ++kt) {                 // BK = 128 fp8 bytes
        #pragma unroll
        for (int i = 0; i < 4; i++) {
            int chunk = i * 256 + t;                 // 1024 chunks of 16B per panel
            int row = chunk >> 3, cin = chunk & 7;
            int ldsoff = (i * 256 + w * 64) * 16;    // wave-uniform base + lane*16
            __builtin_amdgcn_global_load_lds(
                (const __attribute__((address_space(1))) void*)(Ab + (size_t)row * LL + kt * 128 + cin * 16),
                (__attribute__((address_space(3))) void*)(As + ldsoff), 16, 0, 0);
            if (!diag)
                __builtin_amdgcn_global_load_lds(
                    (const __attribute__((address_space(1))) void*)(Bb + (size_t)row * LL + kt * 128 + cin * 16),
                    (__attribute__((address_space(3))) void*)(Bs + ldsoff), 16, 0, 0);
        }
        __syncthreads();
        const unsigned char* Bsel = diag ? As : Bs;
        i32x8 af[4], bg[4];
        #pragma unroll
        for (int m = 0; m < 4; m++)
            af[m] = *(const i32x8*)(As + (wr * 64 + m * 16 + fr) * 128 + fq * 32);
        #pragma unroll
        for (int n = 0; n < 4; n++)
            bg[n] = *(const i32x8*)(Bsel + (wc * 64 + n * 16 + fr) * 128 + fq * 32);
        #pragma unroll
        for (int m = 0; m < 4; m++)
            #pragma unroll
            for (int n = 0; n < 4; n++)
                acc[m][n] = __builtin_amdgcn_mfma_scale_f32_16x16x128_f8f6f4(
                    af[m], bg[n], acc[m][n], 0, 0,
                    0, 0x7F7F7F7F, 0, 0x7F7F7F7F);   // scale = 1.0 in every byte
        __syncthreads();
    }

    // epilogue: emit pairs with sim*4096 <= 2048 (i.e. sim <= 0.5). Expected: none.
    unsigned* zcnt = (unsigned*)&sc[10];
    int gr = bi * 2 + wr, gc = bj * 2 + wc;
    #pragma unroll
    for (int m = 0; m < 4; m++) {
        #pragma unroll
        for (int n = 0; n < 4; n++) {
            #pragma unroll
            for (int r = 0; r < 4; r++) {
                int grow = gr * 64 + m * 16 + fq * 4 + r;
                int gcol = gc * 64 + n * 16 + fr;
                bool z = (acc[m][n][r] <= 2048.0f) && (grow != gcol);
                if (__ballot(z)) {                   // rare path
                    if (z) {
                        unsigned pos = atomicAdd(zcnt, diag ? 1u : 2u);
                        if (pos < ZCAP)
                            zlist[pos] = ((unsigned)grow << 13) | (unsigned)gcol;
                        if (!diag && pos + 1 < ZCAP)
                            zlist[pos + 1] = ((unsigned)gcol << 13) | (unsigned)grow;
                    }
                }
            }
        }
    }
}

// ---------------- fused tail: sums, SAGE+BN+lin+softmax (s), losses, head, output.
__global__ __launch_bounds__(1024) void k_tail(
        const float* __restrict__ xw, const float* __restrict__ xr,
        const float* __restrict__ relb, const float* __restrict__ bng,
        const float* __restrict__ bnb, const float* __restrict__ linw,
        const float* __restrict__ linb, const float* __restrict__ av,
        const float* __restrict__ l1b, const float* __restrict__ l2w,
        const float* __restrict__ l2b, const unsigned* __restrict__ zlist,
        const float* __restrict__ sc, float* __restrict__ s, float* __restrict__ out)
{
    __shared__ float red[16][6];
    __shared__ float bc[8];
    __shared__ float hv[256];
    __shared__ float lg[4];
    int t = threadIdx.x, lane = t & 63, wv = t >> 6;
    unsigned cnt = ((const unsigned*)sc)[10]; if (cnt > ZCAP) cnt = ZCAP;

    // stage A: column sums of xw
    float a0 = 0.f, a1 = 0.f;
    for (int i = t; i < NN; i += 1024) { a0 += xw[i * 2]; a1 += xw[i * 2 + 1]; }
    #pragma unroll
    for (int off = 32; off > 0; off >>= 1) { a0 += __shfl_xor(a0, off); a1 += __shfl_xor(a1, off); }
    if (lane == 0) { red[wv][0] = a0; red[wv][1] = a1; }
    __syncthreads();
    if (t == 0) {
        float x0 = 0.f, x1 = 0.f;
        for (int k = 0; k < 16; k++) { x0 += red[k][0]; x1 += red[k][1]; }
        bc[0] = x0; bc[1] = x1;
    }
    __syncthreads();
    float Sxw0 = bc[0], Sxw1 = bc[1];

    // stage B: y rows + BN sums
    float y[8][2];
    float b0 = 0.f, b1 = 0.f, q0 = 0.f, q1 = 0.f;
    #pragma unroll
    for (int r = 0; r < 8; r++) {
        int i = r * 1024 + t;
        float c0 = 0.f, c1 = 0.f; int zc = 0;
        for (unsigned j = 0; j < cnt; j++) {
            unsigned e = zlist[j];
            if ((int)(e >> 13) == i) {
                unsigned c = e & 8191u;
                c0 += xw[c * 2]; c1 += xw[c * 2 + 1]; zc++;
            }
        }
        float d = fmaxf((float)(8191 - zc), 1.0f);
        float y0 = (Sxw0 - xw[i * 2] - c0) / d + relb[0] + xr[i * 2];
        float y1 = (Sxw1 - xw[i * 2 + 1] - c1) / d + relb[1] + xr[i * 2 + 1];
        y0 = y0 > 0.f ? y0 : 0.01f * y0;
        y1 = y1 > 0.f ? y1 : 0.01f * y1;
        y[r][0] = y0; y[r][1] = y1;
        b0 += y0; b1 += y1; q0 += y0 * y0; q1 += y1 * y1;
    }
    #pragma unroll
    for (int off = 32; off > 0; off >>= 1) {
        b0 += __shfl_xor(b0, off); b1 += __shfl_xor(b1, off);
        q0 += __shfl_xor(q0, off); q1 += __shfl_xor(q1, off);
    }
    if (lane == 0) { red[wv][0] = b0; red[wv][1] = b1; red[wv][2] = q0; red[wv][3] = q1; }
    __syncthreads();
    if (t == 0) {
        float S0 = 0.f, S1 = 0.f, Q0 = 0.f, Q1 = 0.f;
        for (int k = 0; k < 16; k++) { S0 += red[k][0]; S1 += red[k][1]; Q0 += red[k][2]; Q1 += red[k][3]; }
        const float invN = 1.0f / NN;
        float m0 = S0 * invN, m1 = S1 * invN;
        float v0 = Q0 * invN - m0 * m0, v1 = Q1 * invN - m1 * m1;
        bc[0] = m0; bc[1] = m1;
        bc[2] = rsqrtf(v0 + 1e-5f) * bng[0];
        bc[3] = rsqrtf(v1 + 1e-5f) * bng[1];
    }
    __syncthreads();
    float m0 = bc[0], m1 = bc[1], cc0 = bc[2], cc1 = bc[3];

    // stage C: BN apply + lin + leaky + softmax -> s; ent/Gram/colsum sums
    float ent = 0.f, g00 = 0.f, g01 = 0.f, g11 = 0.f, Ss0 = 0.f, Ss1 = 0.f;
    #pragma unroll
    for (int r = 0; r < 8; r++) {
        int i = r * 1024 + t;
        float z0 = (y[r][0] - m0) * cc0 + bnb[0];
        float z1 = (y[r][1] - m1) * cc1 + bnb[1];
        float p0 = z0 * linw[0] + z1 * linw[2] + linb[0];
        float p1 = z0 * linw[1] + z1 * linw[3] + linb[1];
        p0 = p0 > 0.f ? p0 : 0.01f * p0;
        p1 = p1 > 0.f ? p1 : 0.01f * p1;
        float mx = fmaxf(p0, p1);
        float e0 = expf(p0 - mx), e1 = expf(p1 - mx);
        float inv = 1.0f / (e0 + e1);
        float s0 = e0 * inv, s1 = e1 * inv;
        s[i * 2] = s0; s[i * 2 + 1] = s1;
        ent -= s0 * logf(s0 + 1e-15f) + s1 * logf(s1 + 1e-15f);
        g00 += s0 * s0; g01 += s0 * s1; g11 += s1 * s1;
        Ss0 += s0; Ss1 += s1;
    }
    #pragma unroll
    for (int off = 32; off > 0; off >>= 1) {
        ent += __shfl_xor(ent, off);
        g00 += __shfl_xor(g00, off); g01 += __shfl_xor(g01, off); g11 += __shfl_xor(g11, off);
        Ss0 += __shfl_xor(Ss0, off); Ss1 += __shfl_xor(Ss1, off);
    }
    if (lane == 0) {
        red[wv][0] = ent; red[wv][1] = g00; red[wv][2] = g01;
        red[wv][3] = g11; red[wv][4] = Ss0; red[wv][5] = Ss1;
    }
    __syncthreads();
    if (t == 0) {
        float E_ = 0.f, G0 = 0.f, G1 = 0.f, G2 = 0.f, C0 = 0.f, C1 = 0.f;
        for (int k = 0; k < 16; k++) {
            E_ += red[k][0]; G0 += red[k][1]; G1 += red[k][2];
            G2 += red[k][3]; C0 += red[k][4]; C1 += red[k][5];
        }
        bc[0] = E_; bc[1] = G0; bc[2] = G1; bc[3] = G2; bc[4] = C0; bc[5] = C1;
    }
    __syncthreads();

    // stage D: zlist correction to tr(s^T adj s); head matvec finish
    float zc_ = 0.f;
    for (unsigned j = t; j < cnt; j += 1024) {
        unsigned e = zlist[j], r = e >> 13, c = e & 8191u;
        zc_ += s[r * 2] * s[c * 2] + s[r * 2 + 1] * s[c * 2 + 1];
    }
    #pragma unroll
    for (int off = 32; off > 0; off >>= 1) zc_ += __shfl_xor(zc_, off);
    if (lane == 0) red[wv][0] = zc_;
    if (t < 256) hv[t] = fmaxf(av[t] + l1b[t], 0.f);
    __syncthreads();
    if (t < 4) {
        float l = l2b[t];
        for (int j = 0; j < 256; j++) l += hv[j] * l2w[j * 4 + t];
        lg[t] = l;
    }
    __syncthreads();
    if (t == 0) {
        float mx = fmaxf(fmaxf(lg[0], lg[1]), fmaxf(lg[2], lg[3]));
        float e[4], sum = 0.f;
        for (int c = 0; c < 4; c++) { e[c] = expf(lg[c] - mx); sum += e[c]; }
        for (int c = 0; c < 4; c++) out[c] = e[c] / sum;
        float zcorr = 0.f;
        for (int k = 0; k < 16; k++) zcorr += red[k][0];
        float G00 = bc[1], G01 = bc[2], G11 = bc[3];
        float tr2 = bc[4] * bc[4] + bc[5] * bc[5] - G00 - G11 - zcorr;
        float E = 8192.0f * 8191.0f - (float)cnt;
        float fro2 = fmaxf(E - 2.f * tr2 + (G00 * G00 + 2.f * G01 * G01 + G11 * G11), 0.f);
        out[4] = sqrtf(fro2) / (8192.0f * 8192.0f);
        out[5] = bc[0] * (1.0f / NN);
    }
}

extern "C" void kernel_launch(void* const* d_in, const int* in_sizes, int n_in,
                              void* d_out, int out_size, void* d_ws, size_t ws_size,
                              hipStream_t stream) {
    const float* x          = (const float*)d_in[0];
    const float* pool_rel_w = (const float*)d_in[1];
    const float* pool_rel_b = (const float*)d_in[2];
    const float* pool_root_w= (const float*)d_in[3];
    const float* pool_bn_g  = (const float*)d_in[4];
    const float* pool_bn_b  = (const float*)d_in[5];
    const float* pool_lin_w = (const float*)d_in[6];
    const float* pool_lin_b = (const float*)d_in[7];
    const float* emb3_bn_b  = (const float*)d_in[17];
    const float* lin1_w     = (const float*)d_in[18];
    const float* lin1_b     = (const float*)d_in[19];
    const float* lin2_w     = (const float*)d_in[20];
    const float* lin2_b     = (const float*)d_in[21];
    float* out = (float*)d_out;

    char* ws = (char*)d_ws;
    unsigned char* xn = (unsigned char*)ws;                    // 4 MB fp8
    unsigned* zlist = (unsigned*)(ws + (size_t)(4u << 20));    // 8 MB
    float* xw = (float*)(ws + (size_t)(12u << 20));            // 64 KB
    float* xr = xw + NN * 2;                                   // 64 KB
    float* s  = xr + NN * 2;                                   // 64 KB
    float* sc = s + NN * 2;                                    // 16 f
    float* av = sc + 16;                                       // 256 f

    if (ws_size < (size_t)(12u << 20) + 3 * NN * 2 * sizeof(float) + (16 + 256) * sizeof(float)) return;

    hipMemsetAsync(sc, 0, (16 + 256) * sizeof(float), stream);
    k_prep<<<dim3(2056), dim3(256), 0, stream>>>(x, pool_rel_w, pool_root_w,
                                                 emb3_bn_b, lin1_w, xn, xw, xr, av);
    k_sim<<<dim3(2080), dim3(256), 0, stream>>>(xn, zlist, sc);
    k_tail<<<dim3(1), dim3(1024), 0, stream>>>(xw, xr, pool_rel_b, pool_bn_g, pool_bn_b,
                                               pool_lin_w, pool_lin_b, av, lin1_b,
                                               lin2_w, lin2_b, zlist, sc, s, out);
}

// Round 5
// 84.687 us; speedup vs baseline: 1.6388x; 1.0683x over previous
//
#include <hip/hip_runtime.h>

#define NN 8192
#define LL 512
#define ZCAP (2u << 20)

typedef float f32x4 __attribute__((ext_vector_type(4)));
typedef int i32x4 __attribute__((ext_vector_type(4)));
typedef int i32x8 __attribute__((ext_vector_type(8)));
typedef unsigned long long u64;

// float -> fp8 e4m3fn (RNE), input in [0, ~6)
__device__ __forceinline__ unsigned f2fp8(float f) {
    if (f < 0.015625f) {                 // subnormal: steps of 2^-9
        return (unsigned)(int)rintf(f * 512.0f);   // 8 -> 0x08 = min normal, correct
    }
    unsigned u = __builtin_bit_cast(unsigned, f);
    unsigned r = u + 0x7FFFF + ((u >> 20) & 1);
    return ((r >> 20) - 960u) & 0xFFu;
}

// ---------------- K1: rows 0..8191: xn(fp8, x64 scale), xw = x@pool_rel_w, xr = x@pool_root_w
// blocks >= 2048: head matvec partials av[t] += sum_k bnb3[k]*l1w[k,t]
__global__ __launch_bounds__(256) void k_prep(const float* __restrict__ x,
        const float* __restrict__ relw, const float* __restrict__ rootw,
        const float* __restrict__ bnb3, const float* __restrict__ l1w,
        unsigned char* __restrict__ xn, float* __restrict__ xw, float* __restrict__ xr,
        float* __restrict__ av)
{
    if (blockIdx.x >= 2048) {
        int j = blockIdx.x - 2048, t = threadIdx.x;
        float acc = 0.f;
        #pragma unroll
        for (int k = j * 64; k < j * 64 + 64; k++) acc += bnb3[k] * l1w[k * 256 + t];
        atomicAdd(&av[t], acc);
        return;
    }
    int w = threadIdx.x >> 6, lane = threadIdx.x & 63;
    int row = blockIdx.x * 4 + w;
    const float* xp = x + (size_t)row * LL + lane * 8;
    float4 a = *(const float4*)xp;
    float4 b = *(const float4*)(xp + 4);
    float v[8] = {a.x, a.y, a.z, a.w, b.x, b.y, b.z, b.w};
    float ss = 0.f, w0 = 0.f, w1 = 0.f, r0 = 0.f, r1 = 0.f;
    #pragma unroll
    for (int e = 0; e < 8; e++) {
        int k = lane * 8 + e;
        ss += v[e] * v[e];
        w0 += v[e] * relw[k * 2];  w1 += v[e] * relw[k * 2 + 1];
        r0 += v[e] * rootw[k * 2]; r1 += v[e] * rootw[k * 2 + 1];
    }
    #pragma unroll
    for (int off = 32; off > 0; off >>= 1) {
        ss += __shfl_xor(ss, off);
        w0 += __shfl_xor(w0, off); w1 += __shfl_xor(w1, off);
        r0 += __shfl_xor(r0, off); r1 += __shfl_xor(r1, off);
    }
    float inv = 64.0f / fmaxf(sqrtf(ss), 1e-6f);   // x64: e4m3 normal range
    u64 pk = 0;
    #pragma unroll
    for (int e = 0; e < 8; e++) pk |= (u64)f2fp8(v[e] * inv) << (8 * e);
    *(u64*)(xn + (size_t)row * LL + lane * 8) = pk;
    if (lane == 0) {
        xw[row * 2] = w0; xw[row * 2 + 1] = w1;
        xr[row * 2] = r0; xr[row * 2 + 1] = r1;
    }
}

// ---------------- K2: sim*4096 = (64 xn)@(64 xn)^T via MX-fp8 MFMA (scale=1.0),
// triangular 128-tiles (bi<=bj); emit below-threshold off-diag pairs to zlist.
// LDS layout XOR-swizzled (both-sides, rule #21): LDS 16B-slot p of row r holds
// global chunk p^(r&7); staging pre-swizzles the GLOBAL source, LDS dest stays linear.
__global__ __launch_bounds__(256) void k_sim(const unsigned char* __restrict__ xn,
                                             unsigned* __restrict__ zlist,
                                             float* __restrict__ sc)
{
    __shared__ __align__(16) unsigned char As[128 * 128];
    __shared__ __align__(16) unsigned char Bs[128 * 128];
    int b = blockIdx.x, bi = 0, len = 64;
    while (b >= len) { b -= len; len--; bi++; }
    int bj = bi + b;
    const bool diag = (bi == bj);

    int t = threadIdx.x, w = t >> 6, lane = t & 63;
    int wr = w >> 1, wc = w & 1;
    int fr = lane & 15, fq = lane >> 4;

    f32x4 zero = {0.f, 0.f, 0.f, 0.f};
    f32x4 acc[4][4];
    #pragma unroll
    for (int m = 0; m < 4; m++)
        #pragma unroll
        for (int n = 0; n < 4; n++) acc[m][n] = zero;

    const unsigned char* Ab = xn + (size_t)bi * 128 * LL;
    const unsigned char* Bb = xn + (size_t)bj * 128 * LL;

    // swizzled fragment fetch: global chunk j of row rl lives at LDS slot j^(rl&7)
    auto frag = [&](const unsigned char* base, int rl) -> i32x8 {
        const unsigned char* rowp = base + rl * 128;
        i32x4 lo = *(const i32x4*)(rowp + (((fq << 1)    ) ^ (rl & 7)) * 16);
        i32x4 hi = *(const i32x4*)(rowp + (((fq << 1) | 1) ^ (rl & 7)) * 16);
        return __builtin_shufflevector(lo, hi, 0, 1, 2, 3, 4, 5, 6, 7);
    };

    for (int kt = 0; kt < 4; ++kt) {                 // BK = 128 fp8 bytes
        #pragma unroll
        for (int i = 0; i < 4; i++) {
            int chunk = i * 256 + t;                 // 1024 chunks of 16B per panel
            int row = chunk >> 3, c = chunk & 7;
            int js = c ^ (row & 7);                  // pre-swizzled global source chunk
            int ldsoff = (i * 256 + w * 64) * 16;    // wave-uniform base + lane*16 (linear)
            __builtin_amdgcn_global_load_lds(
                (const __attribute__((address_space(1))) void*)(Ab + (size_t)row * LL + kt * 128 + js * 16),
                (__attribute__((address_space(3))) void*)(As + ldsoff), 16, 0, 0);
            if (!diag)
                __builtin_amdgcn_global_load_lds(
                    (const __attribute__((address_space(1))) void*)(Bb + (size_t)row * LL + kt * 128 + js * 16),
                    (__attribute__((address_space(3))) void*)(Bs + ldsoff), 16, 0, 0);
        }
        __syncthreads();
        const unsigned char* Bsel = diag ? As : Bs;
        i32x8 af[4], bg[4];
        #pragma unroll
        for (int m = 0; m < 4; m++)
            af[m] = frag(As, wr * 64 + m * 16 + fr);
        #pragma unroll
        for (int n = 0; n < 4; n++)
            bg[n] = frag(Bsel, wc * 64 + n * 16 + fr);
        #pragma unroll
        for (int m = 0; m < 4; m++)
            #pragma unroll
            for (int n = 0; n < 4; n++)
                acc[m][n] = __builtin_amdgcn_mfma_scale_f32_16x16x128_f8f6f4(
                    af[m], bg[n], acc[m][n], 0, 0,
                    0, 0x7F7F7F7F, 0, 0x7F7F7F7F);   // scale = 1.0 in every byte
        __syncthreads();
    }

    // epilogue: emit pairs with sim*4096 <= 2048 (i.e. sim <= 0.5). Expected: none.
    unsigned* zcnt = (unsigned*)&sc[10];
    int gr = bi * 2 + wr, gc = bj * 2 + wc;
    #pragma unroll
    for (int m = 0; m < 4; m++) {
        #pragma unroll
        for (int n = 0; n < 4; n++) {
            #pragma unroll
            for (int r = 0; r < 4; r++) {
                int grow = gr * 64 + m * 16 + fq * 4 + r;
                int gcol = gc * 64 + n * 16 + fr;
                bool z = (acc[m][n][r] <= 2048.0f) && (grow != gcol);
                if (__ballot(z)) {                   // rare path
                    if (z) {
                        unsigned pos = atomicAdd(zcnt, diag ? 1u : 2u);
                        if (pos < ZCAP)
                            zlist[pos] = ((unsigned)grow << 13) | (unsigned)gcol;
                        if (!diag && pos + 1 < ZCAP)
                            zlist[pos + 1] = ((unsigned)gcol << 13) | (unsigned)grow;
                    }
                }
            }
        }
    }
}

// ---------------- fused tail: sums, SAGE+BN+lin+softmax (s), losses, head, output.
__global__ __launch_bounds__(1024) void k_tail(
        const float* __restrict__ xw, const float* __restrict__ xr,
        const float* __restrict__ relb, const float* __restrict__ bng,
        const float* __restrict__ bnb, const float* __restrict__ linw,
        const float* __restrict__ linb, const float* __restrict__ av,
        const float* __restrict__ l1b, const float* __restrict__ l2w,
        const float* __restrict__ l2b, const unsigned* __restrict__ zlist,
        const float* __restrict__ sc, float* __restrict__ s, float* __restrict__ out)
{
    __shared__ float red[16][6];
    __shared__ float bc[8];
    __shared__ float hv[256];
    __shared__ float lg[4];
    int t = threadIdx.x, lane = t & 63, wv = t >> 6;
    unsigned cnt = ((const unsigned*)sc)[10]; if (cnt > ZCAP) cnt = ZCAP;

    // stage A: column sums of xw
    float a0 = 0.f, a1 = 0.f;
    for (int i = t; i < NN; i += 1024) { a0 += xw[i * 2]; a1 += xw[i * 2 + 1]; }
    #pragma unroll
    for (int off = 32; off > 0; off >>= 1) { a0 += __shfl_xor(a0, off); a1 += __shfl_xor(a1, off); }
    if (lane == 0) { red[wv][0] = a0; red[wv][1] = a1; }
    __syncthreads();
    if (t == 0) {
        float x0 = 0.f, x1 = 0.f;
        for (int k = 0; k < 16; k++) { x0 += red[k][0]; x1 += red[k][1]; }
        bc[0] = x0; bc[1] = x1;
    }
    __syncthreads();
    float Sxw0 = bc[0], Sxw1 = bc[1];

    // stage B: y rows + BN sums
    float y[8][2];
    float b0 = 0.f, b1 = 0.f, q0 = 0.f, q1 = 0.f;
    #pragma unroll
    for (int r = 0; r < 8; r++) {
        int i = r * 1024 + t;
        float c0 = 0.f, c1 = 0.f; int zc = 0;
        for (unsigned j = 0; j < cnt; j++) {
            unsigned e = zlist[j];
            if ((int)(e >> 13) == i) {
                unsigned c = e & 8191u;
                c0 += xw[c * 2]; c1 += xw[c * 2 + 1]; zc++;
            }
        }
        float d = fmaxf((float)(8191 - zc), 1.0f);
        float y0 = (Sxw0 - xw[i * 2] - c0) / d + relb[0] + xr[i * 2];
        float y1 = (Sxw1 - xw[i * 2 + 1] - c1) / d + relb[1] + xr[i * 2 + 1];
        y0 = y0 > 0.f ? y0 : 0.01f * y0;
        y1 = y1 > 0.f ? y1 : 0.01f * y1;
        y[r][0] = y0; y[r][1] = y1;
        b0 += y0; b1 += y1; q0 += y0 * y0; q1 += y1 * y1;
    }
    #pragma unroll
    for (int off = 32; off > 0; off >>= 1) {
        b0 += __shfl_xor(b0, off); b1 += __shfl_xor(b1, off);
        q0 += __shfl_xor(q0, off); q1 += __shfl_xor(q1, off);
    }
    if (lane == 0) { red[wv][0] = b0; red[wv][1] = b1; red[wv][2] = q0; red[wv][3] = q1; }
    __syncthreads();
    if (t == 0) {
        float S0 = 0.f, S1 = 0.f, Q0 = 0.f, Q1 = 0.f;
        for (int k = 0; k < 16; k++) { S0 += red[k][0]; S1 += red[k][1]; Q0 += red[k][2]; Q1 += red[k][3]; }
        const float invN = 1.0f / NN;
        float m0 = S0 * invN, m1 = S1 * invN;
        float v0 = Q0 * invN - m0 * m0, v1 = Q1 * invN - m1 * m1;
        bc[0] = m0; bc[1] = m1;
        bc[2] = rsqrtf(v0 + 1e-5f) * bng[0];
        bc[3] = rsqrtf(v1 + 1e-5f) * bng[1];
    }
    __syncthreads();
    float m0 = bc[0], m1 = bc[1], cc0 = bc[2], cc1 = bc[3];

    // stage C: BN apply + lin + leaky + softmax -> s; ent/Gram/colsum sums
    float ent = 0.f, g00 = 0.f, g01 = 0.f, g11 = 0.f, Ss0 = 0.f, Ss1 = 0.f;
    #pragma unroll
    for (int r = 0; r < 8; r++) {
        int i = r * 1024 + t;
        float z0 = (y[r][0] - m0) * cc0 + bnb[0];
        float z1 = (y[r][1] - m1) * cc1 + bnb[1];
        float p0 = z0 * linw[0] + z1 * linw[2] + linb[0];
        float p1 = z0 * linw[1] + z1 * linw[3] + linb[1];
        p0 = p0 > 0.f ? p0 : 0.01f * p0;
        p1 = p1 > 0.f ? p1 : 0.01f * p1;
        float mx = fmaxf(p0, p1);
        float e0 = expf(p0 - mx), e1 = expf(p1 - mx);
        float inv = 1.0f / (e0 + e1);
        float s0 = e0 * inv, s1 = e1 * inv;
        s[i * 2] = s0; s[i * 2 + 1] = s1;
        ent -= s0 * logf(s0 + 1e-15f) + s1 * logf(s1 + 1e-15f);
        g00 += s0 * s0; g01 += s0 * s1; g11 += s1 * s1;
        Ss0 += s0; Ss1 += s1;
    }
    #pragma unroll
    for (int off = 32; off > 0; off >>= 1) {
        ent += __shfl_xor(ent, off);
        g00 += __shfl_xor(g00, off); g01 += __shfl_xor(g01, off); g11 += __shfl_xor(g11, off);
        Ss0 += __shfl_xor(Ss0, off); Ss1 += __shfl_xor(Ss1, off);
    }
    if (lane == 0) {
        red[wv][0] = ent; red[wv][1] = g00; red[wv][2] = g01;
        red[wv][3] = g11; red[wv][4] = Ss0; red[wv][5] = Ss1;
    }
    __syncthreads();
    if (t == 0) {
        float E_ = 0.f, G0 = 0.f, G1 = 0.f, G2 = 0.f, C0 = 0.f, C1 = 0.f;
        for (int k = 0; k < 16; k++) {
            E_ += red[k][0]; G0 += red[k][1]; G1 += red[k][2];
            G2 += red[k][3]; C0 += red[k][4]; C1 += red[k][5];
        }
        bc[0] = E_; bc[1] = G0; bc[2] = G1; bc[3] = G2; bc[4] = C0; bc[5] = C1;
    }
    __syncthreads();

    // stage D: zlist correction to tr(s^T adj s); head matvec finish
    float zc_ = 0.f;
    for (unsigned j = t; j < cnt; j += 1024) {
        unsigned e = zlist[j], r = e >> 13, c = e & 8191u;
        zc_ += s[r * 2] * s[c * 2] + s[r * 2 + 1] * s[c * 2 + 1];
    }
    #pragma unroll
    for (int off = 32; off > 0; off >>= 1) zc_ += __shfl_xor(zc_, off);
    if (lane == 0) red[wv][0] = zc_;
    if (t < 256) hv[t] = fmaxf(av[t] + l1b[t], 0.f);
    __syncthreads();
    if (t < 4) {
        float l = l2b[t];
        for (int j = 0; j < 256; j++) l += hv[j] * l2w[j * 4 + t];
        lg[t] = l;
    }
    __syncthreads();
    if (t == 0) {
        float mx = fmaxf(fmaxf(lg[0], lg[1]), fmaxf(lg[2], lg[3]));
        float e[4], sum = 0.f;
        for (int c = 0; c < 4; c++) { e[c] = expf(lg[c] - mx); sum += e[c]; }
        for (int c = 0; c < 4; c++) out[c] = e[c] / sum;
        float zcorr = 0.f;
        for (int k = 0; k < 16; k++) zcorr += red[k][0];
        float G00 = bc[1], G01 = bc[2], G11 = bc[3];
        float tr2 = bc[4] * bc[4] + bc[5] * bc[5] - G00 - G11 - zcorr;
        float E = 8192.0f * 8191.0f - (float)cnt;
        float fro2 = fmaxf(E - 2.f * tr2 + (G00 * G00 + 2.f * G01 * G01 + G11 * G11), 0.f);
        out[4] = sqrtf(fro2) / (8192.0f * 8192.0f);
        out[5] = bc[0] * (1.0f / NN);
    }
}

extern "C" void kernel_launch(void* const* d_in, const int* in_sizes, int n_in,
                              void* d_out, int out_size, void* d_ws, size_t ws_size,
                              hipStream_t stream) {
    const float* x          = (const float*)d_in[0];
    const float* pool_rel_w = (const float*)d_in[1];
    const float* pool_rel_b = (const float*)d_in[2];
    const float* pool_root_w= (const float*)d_in[3];
    const float* pool_bn_g  = (const float*)d_in[4];
    const float* pool_bn_b  = (const float*)d_in[5];
    const float* pool_lin_w = (const float*)d_in[6];
    const float* pool_lin_b = (const float*)d_in[7];
    const float* emb3_bn_b  = (const float*)d_in[17];
    const float* lin1_w     = (const float*)d_in[18];
    const float* lin1_b     = (const float*)d_in[19];
    const float* lin2_w     = (const float*)d_in[20];
    const float* lin2_b     = (const float*)d_in[21];
    float* out = (float*)d_out;

    char* ws = (char*)d_ws;
    unsigned char* xn = (unsigned char*)ws;                    // 4 MB fp8
    unsigned* zlist = (unsigned*)(ws + (size_t)(4u << 20));    // 8 MB
    float* xw = (float*)(ws + (size_t)(12u << 20));            // 64 KB
    float* xr = xw + NN * 2;                                   // 64 KB
    float* s  = xr + NN * 2;                                   // 64 KB
    float* sc = s + NN * 2;                                    // 16 f
    float* av = sc + 16;                                       // 256 f

    if (ws_size < (size_t)(12u << 20) + 3 * NN * 2 * sizeof(float) + (16 + 256) * sizeof(float)) return;

    hipMemsetAsync(sc, 0, (16 + 256) * sizeof(float), stream);
    k_prep<<<dim3(2056), dim3(256), 0, stream>>>(x, pool_rel_w, pool_root_w,
                                                 emb3_bn_b, lin1_w, xn, xw, xr, av);
    k_sim<<<dim3(2080), dim3(256), 0, stream>>>(xn, zlist, sc);
    k_tail<<<dim3(1), dim3(1024), 0, stream>>>(xw, xr, pool_rel_b, pool_bn_g, pool_bn_b,
                                               pool_lin_w, pool_lin_b, av, lin1_b,
                                               lin2_w, lin2_b, zlist, sc, s, out);
}